// Round 3
// baseline (637.256 us; speedup 1.0000x reference)
//
#include <hip/hip_runtime.h>

#define N_NODES 100000
#define N_EDGES 1200000
// D_IN = D_HID = 64, D_OUT = 16
static_assert(N_EDGES % 64 == 0, "edge batching assumes full 64-edge batches");

// ---------------------------------------------------------------------------
// k_edge1: agg1[dst][d] += x[src][d] * ew[e];  cnt[dst] += 1
// Wave processes 64 edges per batch: metadata loaded coalesced (lane e), then
// broadcast via readlane (SGPR indices -> scalar-base addressing for the
// gather). Per edge: 1 coalesced 256B gather of x[src], 64 f32 atomics.
// ---------------------------------------------------------------------------
__global__ __launch_bounds__(256) void k_edge1(const int* __restrict__ ei,
                                               const float* __restrict__ ew,
                                               const float* __restrict__ x,
                                               float* __restrict__ agg1,
                                               float* __restrict__ cnt) {
    const int lane = threadIdx.x & 63;
    const int wid  = blockIdx.x * 4 + (threadIdx.x >> 6);
    const int nw   = gridDim.x * 4;
    for (int base = wid * 64; base < N_EDGES; base += nw * 64) {
        const int e   = base + lane;
        const int srcv = ei[e];
        const int dstv = ei[N_EDGES + e];
        const float ewv = ew[e];
        atomicAdd(&cnt[dstv], 1.0f);           // in-degree (per edge, own lane)
        #pragma unroll 4
        for (int it = 0; it < 64; ++it) {
            int   s = __builtin_amdgcn_readlane(srcv, it);
            int   d = __builtin_amdgcn_readlane(dstv, it);
            float w = __int_as_float(__builtin_amdgcn_readlane(__float_as_int(ewv), it));
            float v = x[(size_t)s * 64 + lane] * w;
            atomicAdd(&agg1[(size_t)d * 64 + lane], v);
        }
    }
}

// ---------------------------------------------------------------------------
// k_node1: per node (wave per node, lane d = dim d):
//   a[d]   = agg1[n][d] / max(cnt,1)
//   h[d]   = relu(a @ W1l + x[n] @ W1r + b1)[d]      (all in registers)
//   z2[j]  = sum_k h[k]*W2l[k][j]   (j in 0..15)     -> scattered in layer 2
//   hw2r[j]= sum_k h[k]*W2r[k][j]                    -> added in epilogue
// h never touches HBM. w1l/w1r reads: 2 lanes/bank (free). w2l/w2r padded to
// stride 17: 4-way bank conflict -> 2-way (free).
// ---------------------------------------------------------------------------
__global__ __launch_bounds__(256) void k_node1(const float* __restrict__ x,
                                               const float* __restrict__ agg1,
                                               const float* __restrict__ cnt,
                                               const float* __restrict__ W1l,
                                               const float* __restrict__ b1,
                                               const float* __restrict__ W1r,
                                               const float* __restrict__ W2l,
                                               const float* __restrict__ W2r,
                                               float* __restrict__ z2,
                                               float* __restrict__ hw2r) {
    __shared__ float w1l[64 * 64];
    __shared__ float w1r[64 * 64];
    __shared__ float w2l[64 * 17];   // stride-17 pad (bank-conflict fix)
    __shared__ float w2r[64 * 17];
    __shared__ float b1s[64];
    for (int i = threadIdx.x; i < 64 * 64; i += 256) { w1l[i] = W1l[i]; w1r[i] = W1r[i]; }
    for (int i = threadIdx.x; i < 64 * 16; i += 256) {
        int k = i >> 4, j = i & 15;
        w2l[k * 17 + j] = W2l[i];
        w2r[k * 17 + j] = W2r[i];
    }
    if (threadIdx.x < 64) b1s[threadIdx.x] = b1[threadIdx.x];
    __syncthreads();
    const int lane = threadIdx.x & 63;
    const int wid  = blockIdx.x * 4 + (threadIdx.x >> 6);
    const int nw   = gridDim.x * 4;
    const int j = lane & 15, g = lane >> 4;
    for (int n = wid; n < N_NODES; n += nw) {
        float c = cnt[n];
        c = c > 1.f ? c : 1.f;
        float av = agg1[(size_t)n * 64 + lane] / c;  // mean neighbor feature
        float xr = x[(size_t)n * 64 + lane];         // self feature
        float acc = b1s[lane];
        #pragma unroll
        for (int k = 0; k < 64; ++k) {
            float ak = __shfl(av, k);
            float xk = __shfl(xr, k);
            acc = fmaf(ak, w1l[k * 64 + lane], acc);
            acc = fmaf(xk, w1r[k * 64 + lane], acc);
        }
        float hval = acc > 0.f ? acc : 0.f;          // ReLU; h stays in regs

        // z2 = h @ W2l, hw2r = h @ W2r (16 outputs each; 4 lane-groups each
        // cover 16 of the 64 k values, then xor-tree combine)
        float az = 0.f, ar = 0.f;
        #pragma unroll
        for (int i = 0; i < 16; ++i) {
            int   k  = g * 16 + i;
            float hk = __shfl(hval, k);
            az = fmaf(hk, w2l[k * 17 + j], az);
            ar = fmaf(hk, w2r[k * 17 + j], ar);
        }
        az += __shfl_xor(az, 16); az += __shfl_xor(az, 32);
        ar += __shfl_xor(ar, 16); ar += __shfl_xor(ar, 32);
        if (g == 0) {
            z2[(size_t)n * 16 + j]   = az;
            hw2r[(size_t)n * 16 + j] = ar;
        }
    }
}

// ---------------------------------------------------------------------------
// k_edge2: agg2[dst][j] += z2[src][j] * ew[e]
// Wave per 64-edge batch; 4 edges concurrently (16 lanes each). Linearity:
// mean(h)@W2l == mean(h@W2l) -> scatter 16 dims, not 64.
// ---------------------------------------------------------------------------
__global__ __launch_bounds__(256) void k_edge2(const int* __restrict__ ei,
                                               const float* __restrict__ ew,
                                               const float* __restrict__ z2,
                                               float* __restrict__ agg2) {
    const int lane = threadIdx.x & 63;
    const int wid  = blockIdx.x * 4 + (threadIdx.x >> 6);
    const int nw   = gridDim.x * 4;
    const int j = lane & 15, g = lane >> 4;
    for (int base = wid * 64; base < N_EDGES; base += nw * 64) {
        const int e    = base + lane;
        const int srcv = ei[e];
        const int dstv = ei[N_EDGES + e];
        const float ewv = ew[e];
        #pragma unroll 4
        for (int t = 0; t < 16; ++t) {
            int eidx = t * 4 + g;                  // varies per lane-group
            int   s = __shfl(srcv, eidx);
            int   d = __shfl(dstv, eidx);
            float w = __shfl(ewv, eidx);
            float v = z2[(size_t)s * 16 + j] * w;
            atomicAdd(&agg2[(size_t)d * 16 + j], v);
        }
    }
}

// ---------------------------------------------------------------------------
// k_out: out[n][j] = agg2[n][j]/max(cnt[n],1) + b2[j] + hw2r[n][j]
// ---------------------------------------------------------------------------
__global__ __launch_bounds__(256) void k_out(const float* __restrict__ agg2,
                                             const float* __restrict__ cnt,
                                             const float* __restrict__ b2,
                                             const float* __restrict__ hw2r,
                                             float* __restrict__ out) {
    const int tid    = blockIdx.x * 256 + threadIdx.x;
    const int stride = gridDim.x * 256;
    for (int i = tid; i < N_NODES * 16; i += stride) {
        int n = i >> 4, j = i & 15;
        float c = cnt[n];
        c = c > 1.f ? c : 1.f;
        out[i] = agg2[i] / c + b2[j] + hw2r[i];
    }
}

extern "C" void kernel_launch(void* const* d_in, const int* in_sizes, int n_in,
                              void* d_out, int out_size, void* d_ws, size_t ws_size,
                              hipStream_t stream) {
    const float* x   = (const float*)d_in[0];
    const int*   ei  = (const int*)d_in[1];   // [2, E]: row0=src, row1=dst
    const float* ew  = (const float*)d_in[2];
    const float* W1l = (const float*)d_in[3];
    const float* b1  = (const float*)d_in[4];
    const float* W1r = (const float*)d_in[5];
    const float* W2l = (const float*)d_in[6];
    const float* b2  = (const float*)d_in[7];
    const float* W2r = (const float*)d_in[8];
    float* out = (float*)d_out;

    // Workspace layout (floats). Zeroed region first (agg1|agg2|cnt).
    float* ws   = (float*)d_ws;
    float* agg1 = ws;                           // N*64
    float* agg2 = agg1 + (size_t)N_NODES * 64;  // N*16
    float* cnt  = agg2 + (size_t)N_NODES * 16;  // N
    float* z2   = cnt  + (size_t)N_NODES;       // N*16
    float* hw2r = z2   + (size_t)N_NODES * 16;  // N*16

    hipMemsetAsync(ws, 0, (size_t)N_NODES * (64 + 16 + 1) * sizeof(float), stream);

    k_edge1<<<2048, 256, 0, stream>>>(ei, ew, x, agg1, cnt);
    k_node1<<<2048, 256, 0, stream>>>(x, agg1, cnt, W1l, b1, W1r, W2l, W2r, z2, hw2r);
    k_edge2<<<2048, 256, 0, stream>>>(ei, ew, z2, agg2);
    k_out<<<1024, 256, 0, stream>>>(agg2, cnt, b2, hw2r, out);
}

// Round 4
// 610.796 us; speedup vs baseline: 1.0433x; 1.0433x over previous
//
#include <hip/hip_runtime.h>

#define N_NODES 100000
#define N_EDGES 1200000
#define NB_SCAN ((N_NODES + 1023) / 1024)   // 98 blocks of 1024 elements
// D_IN = D_HID = 64, D_OUT = 16

// ---------------------------------------------------------------------------
// CSR build: deg histogram -> exclusive scan (3 tiny kernels) -> cursor fill.
// Replaces all f32 scatter atomics with gather-side accumulation.
// ---------------------------------------------------------------------------
__global__ __launch_bounds__(256) void k_hist(const int* __restrict__ ei,
                                              int* __restrict__ deg) {
    int e = blockIdx.x * 256 + threadIdx.x;
    if (e < N_EDGES) atomicAdd(&deg[ei[N_EDGES + e]], 1);
}

__global__ __launch_bounds__(256) void k_scanA(const int* __restrict__ deg,
                                               int* __restrict__ bsum) {
    const int b = blockIdx.x, t = threadIdx.x;
    const int base = b * 1024 + t * 4;
    int s = 0;
    #pragma unroll
    for (int i = 0; i < 4; ++i) {
        int idx = base + i;
        if (idx < N_NODES) s += deg[idx];
    }
    #pragma unroll
    for (int off = 1; off < 64; off <<= 1) s += __shfl_xor(s, off);
    __shared__ int part[4];
    if ((t & 63) == 0) part[t >> 6] = s;
    __syncthreads();
    if (t == 0) bsum[b] = part[0] + part[1] + part[2] + part[3];
}

__global__ void k_scanB(const int* __restrict__ bsum, int* __restrict__ boff) {
    if (threadIdx.x == 0) {
        int acc = 0;
        for (int i = 0; i < NB_SCAN; ++i) { boff[i] = acc; acc += bsum[i]; }
    }
}

__global__ __launch_bounds__(256) void k_scanC(const int* __restrict__ deg,
                                               const int* __restrict__ boff,
                                               int* __restrict__ row_ptr) {
    __shared__ int tot[256];
    const int b = blockIdx.x, t = threadIdx.x;
    const int base = b * 1024 + t * 4;
    int d[4]; int s = 0;
    #pragma unroll
    for (int i = 0; i < 4; ++i) {
        int idx = base + i;
        d[i] = (idx < N_NODES) ? deg[idx] : 0;
        s += d[i];
    }
    tot[t] = s;
    __syncthreads();
    // Hillis-Steele inclusive scan (read-phase / barrier / write-phase)
    for (int off = 1; off < 256; off <<= 1) {
        int v = (t >= off) ? tot[t - off] : 0;
        __syncthreads();
        tot[t] += v;
        __syncthreads();
    }
    int run = boff[b] + tot[t] - s;   // exclusive prefix for this thread
    #pragma unroll
    for (int i = 0; i < 4; ++i) {
        int idx = base + i;
        if (idx < N_NODES) { row_ptr[idx] = run; run += d[i]; }
    }
    if (b == 0 && t == 0) row_ptr[N_NODES] = N_EDGES;
}

__global__ __launch_bounds__(256) void k_fill(const int* __restrict__ ei,
                                              const float* __restrict__ ew,
                                              int* __restrict__ cursor,
                                              uint2* __restrict__ csr) {
    int e = blockIdx.x * 256 + threadIdx.x;
    if (e < N_EDGES) {
        int src = ei[e];
        int dst = ei[N_EDGES + e];
        int pos = atomicAdd(&cursor[dst], 1);
        csr[pos] = make_uint2((unsigned)src, __float_as_uint(ew[e]));
    }
}

// ---------------------------------------------------------------------------
// k_l1: fused layer-1 gather + node update (wave per dst node, lane d = dim d):
//   acc[d]  = sum_{in-edges} x[src][d] * w_e        (register accumulation)
//   a[d]    = acc[d] / max(deg,1)
//   h[d]    = relu(a @ W1l + x[n] @ W1r + b1)[d]    (all in registers)
//   z2[j]   = (h @ W2l)[j],  hw2r[j] = (h @ W2r)[j]  (j in 0..15)
// No atomics, no agg1 buffer. Edge metadata: one coalesced 512B load per 64
// edges, broadcast via readlane (uniform index -> SGPR).
// ---------------------------------------------------------------------------
__global__ __launch_bounds__(256) void k_l1(const float* __restrict__ x,
                                            const int* __restrict__ row_ptr,
                                            const uint2* __restrict__ csr,
                                            const float* __restrict__ W1l,
                                            const float* __restrict__ b1,
                                            const float* __restrict__ W1r,
                                            const float* __restrict__ W2l,
                                            const float* __restrict__ W2r,
                                            float* __restrict__ z2,
                                            float* __restrict__ hw2r) {
    __shared__ float w1l[64 * 64];
    __shared__ float w1r[64 * 64];
    __shared__ float w2l[64 * 17];   // stride-17: 4-way bank conflict -> 2-way
    __shared__ float w2r[64 * 17];
    __shared__ float b1s[64];
    for (int i = threadIdx.x; i < 64 * 64; i += 256) { w1l[i] = W1l[i]; w1r[i] = W1r[i]; }
    for (int i = threadIdx.x; i < 64 * 16; i += 256) {
        int k = i >> 4, j = i & 15;
        w2l[k * 17 + j] = W2l[i];
        w2r[k * 17 + j] = W2r[i];
    }
    if (threadIdx.x < 64) b1s[threadIdx.x] = b1[threadIdx.x];
    __syncthreads();
    const int lane = threadIdx.x & 63;
    const int wid  = blockIdx.x * 4 + (threadIdx.x >> 6);
    const int nw   = gridDim.x * 4;
    const int j = lane & 15, g = lane >> 4;
    for (int n = wid; n < N_NODES; n += nw) {
        const int r0 = row_ptr[n], r1 = row_ptr[n + 1];
        const int deg = r1 - r0;
        float acc = 0.f;
        for (int base = r0; base < r1; base += 64) {
            const int m = r1 - base < 64 ? r1 - base : 64;
            uint2 sw = make_uint2(0u, 0u);
            if (base + lane < r1) sw = csr[base + lane];
            const int   sv = (int)sw.x;
            const int   wv = (int)sw.y;
            for (int it = 0; it < m; ++it) {
                int   s = __builtin_amdgcn_readlane(sv, it);
                float w = __int_as_float(__builtin_amdgcn_readlane(wv, it));
                acc = fmaf(x[(size_t)s * 64 + lane], w, acc);
            }
        }
        const float inv = 1.f / (float)(deg > 0 ? deg : 1);
        const float av  = acc * inv;            // mean neighbor feature
        const float xr  = x[(size_t)n * 64 + lane];
        float hacc = b1s[lane];
        #pragma unroll
        for (int k = 0; k < 64; ++k) {
            float ak = __shfl(av, k);
            float xk = __shfl(xr, k);
            hacc = fmaf(ak, w1l[k * 64 + lane], hacc);
            hacc = fmaf(xk, w1r[k * 64 + lane], hacc);
        }
        const float hval = hacc > 0.f ? hacc : 0.f;   // ReLU, stays in regs

        float az = 0.f, ar = 0.f;
        #pragma unroll
        for (int i = 0; i < 16; ++i) {
            int   k  = g * 16 + i;
            float hk = __shfl(hval, k);
            az = fmaf(hk, w2l[k * 17 + j], az);
            ar = fmaf(hk, w2r[k * 17 + j], ar);
        }
        az += __shfl_xor(az, 16); az += __shfl_xor(az, 32);
        ar += __shfl_xor(ar, 16); ar += __shfl_xor(ar, 32);
        if (g == 0) {
            z2[(size_t)n * 16 + j]   = az;
            hw2r[(size_t)n * 16 + j] = ar;
        }
    }
}

// ---------------------------------------------------------------------------
// k_l2: fused layer-2 gather + epilogue (wave per dst node).
// 4 lane-groups of 16; group g takes edges r0+g, r0+g+4, ...; xor-combine.
//   out[n][j] = (sum z2[src][j]*w)/max(deg,1) + b2[j] + hw2r[n][j]
// Linearity: mean(h)@W2l == mean(h@W2l) -> 16 dims through the gather.
// ---------------------------------------------------------------------------
__global__ __launch_bounds__(256) void k_l2(const float* __restrict__ z2,
                                            const int* __restrict__ row_ptr,
                                            const uint2* __restrict__ csr,
                                            const float* __restrict__ b2,
                                            const float* __restrict__ hw2r,
                                            float* __restrict__ out) {
    const int lane = threadIdx.x & 63;
    const int wid  = blockIdx.x * 4 + (threadIdx.x >> 6);
    const int nw   = gridDim.x * 4;
    const int j = lane & 15, g = lane >> 4;
    for (int n = wid; n < N_NODES; n += nw) {
        const int r0 = row_ptr[n], r1 = row_ptr[n + 1];
        const int deg = r1 - r0;
        float a = 0.f;
        for (int i = r0 + g; i < r1; i += 4) {
            uint2 sw = csr[i];
            a = fmaf(z2[(size_t)sw.x * 16 + j], __int_as_float((int)sw.y), a);
        }
        a += __shfl_xor(a, 16); a += __shfl_xor(a, 32);
        if (g == 0) {
            const float inv = 1.f / (float)(deg > 0 ? deg : 1);
            out[(size_t)n * 16 + j] = a * inv + b2[j] + hw2r[(size_t)n * 16 + j];
        }
    }
}

extern "C" void kernel_launch(void* const* d_in, const int* in_sizes, int n_in,
                              void* d_out, int out_size, void* d_ws, size_t ws_size,
                              hipStream_t stream) {
    const float* x   = (const float*)d_in[0];
    const int*   ei  = (const int*)d_in[1];   // [2, E]: row0=src, row1=dst
    const float* ew  = (const float*)d_in[2];
    const float* W1l = (const float*)d_in[3];
    const float* b1  = (const float*)d_in[4];
    const float* W1r = (const float*)d_in[5];
    const float* W2l = (const float*)d_in[6];
    const float* b2  = (const float*)d_in[7];
    const float* W2r = (const float*)d_in[8];
    float* out = (float*)d_out;

    // Workspace layout (csr first: 8B alignment at base).
    char* w = (char*)d_ws;
    uint2* csr     = (uint2*)w;  w += (size_t)N_EDGES * 8;
    float* z2      = (float*)w;  w += (size_t)N_NODES * 16 * 4;
    float* hw2r    = (float*)w;  w += (size_t)N_NODES * 16 * 4;
    int*   deg     = (int*)w;    w += (size_t)N_NODES * 4;
    int*   row_ptr = (int*)w;    w += (size_t)(N_NODES + 1) * 4;
    int*   cursor  = (int*)w;    w += (size_t)N_NODES * 4;
    int*   bsum    = (int*)w;    w += 128 * 4;
    int*   boff    = (int*)w;

    hipMemsetAsync(deg, 0, (size_t)N_NODES * 4, stream);

    k_hist <<<(N_EDGES + 255) / 256, 256, 0, stream>>>(ei, deg);
    k_scanA<<<NB_SCAN, 256, 0, stream>>>(deg, bsum);
    k_scanB<<<1, 64, 0, stream>>>(bsum, boff);
    k_scanC<<<NB_SCAN, 256, 0, stream>>>(deg, boff, row_ptr);
    hipMemcpyAsync(cursor, row_ptr, (size_t)N_NODES * 4,
                   hipMemcpyDeviceToDevice, stream);
    k_fill <<<(N_EDGES + 255) / 256, 256, 0, stream>>>(ei, ew, cursor, csr);
    k_l1   <<<2048, 256, 0, stream>>>(x, row_ptr, csr, W1l, b1, W1r, W2l, W2r, z2, hw2r);
    k_l2   <<<1024, 256, 0, stream>>>(z2, row_ptr, csr, b2, hw2r, out);
}